// Round 4
// baseline (327.316 us; speedup 1.0000x reference)
//
#include <hip/hip_runtime.h>

typedef unsigned short u16;
typedef unsigned int u32;

typedef __attribute__((ext_vector_type(8))) __bf16 bf16x8;
typedef __attribute__((ext_vector_type(4))) float floatx4;

#define B_ 2
#define L_ 2048
#define H_ 16
#define E_ 64
#define QK_ELEMS (B_ * H_ * L_ * E_) /* 4194304 elems; bf16 = 8 MB */

// pack two fp32 -> two bf16 (round-to-nearest, ties away; err <= 1 ulp bf16)
static __device__ __forceinline__ u32 pk2bf(float a, float b) {
  u32 ua = __builtin_bit_cast(u32, a), ub = __builtin_bit_cast(u32, b);
  return ((ua + 0x8000u) >> 16) | (((ub + 0x8000u) >> 16) << 16);
}
static __device__ __forceinline__ u16 f2bf1(float a) {
  return (u16)((__builtin_bit_cast(u32, a) + 0x8000u) >> 16);
}

// RoPE 4 pairs in fp32: pair m uses freq idx pbase+m, theta=10000^(-j/16).
// v_sin/v_cos take revolutions; fract() keeps arg in range (err ~2e-4 rad at l=2047,
// far below bf16 quantization of the operands).
static __device__ __forceinline__ void rope_pairs(float* x, float pos, int pbase) {
  const float LB = 0.83048202372184058696f;   // log2(10000)/16
  const float I2P = 0.15915494309189533577f;  // 1/(2*pi)
#pragma unroll
  for (int m = 0; m < 4; ++m) {
    float fr = exp2f(-(float)(pbase + m) * LB) * I2P;
    float a = pos * fr;
    a -= floorf(a);
    float s = __builtin_amdgcn_sinf(a);
    float c = __builtin_amdgcn_cosf(a);
    float e0 = x[2 * m], e1 = x[2 * m + 1];
    x[2 * m] = c * e0 - s * e1;
    x[2 * m + 1] = c * e1 + s * e0;
  }
}

// ---------- prepass 1: RoPE K (fp32 in) -> bf16 (B,H,L,E) ----------
__global__ __launch_bounds__(256) void rope_k(const float* __restrict__ K,
                                              u16* __restrict__ Kr) {
  int t = threadIdx.x;
  int R = blockIdx.x * 32 + (t >> 3);     // row id in (b,l,h) order
  int chunk = t & 7, e0 = chunk << 3;
  int b = R >> 15, l = (R >> 4) & (L_ - 1), h = R & 15;
  const float* src = K + ((size_t)R << 6) + e0;
  float4 A = *(const float4*)src, Bv = *(const float4*)(src + 4);
  float x[8] = {A.x, A.y, A.z, A.w, Bv.x, Bv.y, Bv.z, Bv.w};
  if (chunk < 4) rope_pairs(x, (float)l, chunk * 4);  // dims < 32 rotate
  uint4 o;
  o.x = pk2bf(x[0], x[1]); o.y = pk2bf(x[2], x[3]);
  o.z = pk2bf(x[4], x[5]); o.w = pk2bf(x[6], x[7]);
  *(uint4*)(Kr + (((size_t)(b * H_ + h) * L_ + l) << 6) + e0) = o;
}

// ---------- prepass 2: V (fp32, B,L,H,E) -> VT (bf16, B,H,E,L) ----------
__global__ __launch_bounds__(256) void transpose_v(const float* __restrict__ V,
                                                   u16* __restrict__ VT) {
  __shared__ u16 tile[64][65];
  int blk = blockIdx.x;             // 32 bh * 32 ltiles
  int bh = blk & 31, lt = blk >> 5;
  int b = bh >> 4, h = bh & 15;
  int t = threadIdx.x;
  int l0 = lt << 6;
#pragma unroll
  for (int it = 0; it < 2; ++it) {
    int ll = (t >> 3) + (it << 5);
    int dc = (t & 7) << 3;
    const float* src = V + (((size_t)(b * L_ + l0 + ll) * H_ + h) << 6) + dc;
    float4 A = *(const float4*)src, Bv = *(const float4*)(src + 4);
    tile[ll][dc + 0] = f2bf1(A.x); tile[ll][dc + 1] = f2bf1(A.y);
    tile[ll][dc + 2] = f2bf1(A.z); tile[ll][dc + 3] = f2bf1(A.w);
    tile[ll][dc + 4] = f2bf1(Bv.x); tile[ll][dc + 5] = f2bf1(Bv.y);
    tile[ll][dc + 6] = f2bf1(Bv.z); tile[ll][dc + 7] = f2bf1(Bv.w);
  }
  __syncthreads();
  int e = t >> 2, lg = (t & 3) << 4;
  u32 pk[8];
#pragma unroll
  for (int i = 0; i < 8; ++i)
    pk[i] = (u32)tile[lg + 2 * i][e] | ((u32)tile[lg + 2 * i + 1][e] << 16);
  u16* dst = VT + (((size_t)bh * E_ + e) * L_) + l0 + lg;
  uint4 o0; o0.x = pk[0]; o0.y = pk[1]; o0.z = pk[2]; o0.w = pk[3];
  uint4 o1; o1.x = pk[4]; o1.y = pk[5]; o1.z = pk[6]; o1.w = pk[7];
  *(uint4*)dst = o0;
  *(uint4*)(dst + 8) = o1;
}

// ---------- main flash kernel ----------
// 16 q-rows per wave, 32-key steps. mfma_f32_16x16x32_bf16 lane maps (m89/m120):
//   A[m=lane&15][k=quad*8+j]   B[k=quad*8+j][n=lane&15]   C/D: col=lane&15, row=quad*4+reg
// S^T = MFMA(A=K,B=Q): lane holds S[q=l16][s=ch*16+quad*4+reg] -> consecutive s in regs
// -> pack bf16 pairs in-register -> 2x ds_write_b64 in A-layout -> 1x ds_read_b128.
// Static softmax max (|score*scale+bias| < ~9, exp2 safe). Row-sum l via MFMA vs ones
// (C rows align with O rows). K/V register prefetch, unroll-by-2 ping-pong.
__global__ __launch_bounds__(256, 4) void flash(
    const float* __restrict__ Q, const u16* __restrict__ Kr,
    const u16* __restrict__ VT, const float* __restrict__ bw,
    float* __restrict__ out) {
  __shared__ __align__(16) u32 pabuf[4][16 * 20];  // per-wave; row stride 20 words
  const int tid = threadIdx.x;
  const int wid = tid >> 6, lane = tid & 63;
  const int quad = lane >> 4, l16 = lane & 15;
  const int bh = blockIdx.x & 31;     // blockIdx%8 == bh%8 -> XCD L2 locality
  const int g = blockIdx.x >> 5;      // 0..31
  // waves in a block share (g&3) -> same t0 class -> equal step count (balanced)
  const int rowblk = (wid << 5) + g;  // 0..127
  const int row0 = rowblk << 4;
  const int b = bh >> 4, h = bh & 15;
  const int t0 = (g & 3) << 4;        // row0 & 63
  const int var_l = rowblk >> 2;
  const int nst = ((g & 3) >> 1) + 1; // 32-key steps per 64-key block
  const int T = nst << 5;
  const int shift = (nst == 2) ? 5 : 6;

  const u16* Kb = Kr + ((size_t)bh << 17);
  const u16* Vb = VT + ((size_t)bh << 17);

  const float L2E = 1.4426950408889634f;
  const float SCL2 = 0.125f * L2E;
  const float bld = bw[h] * L2E, bls = bw[H_ + h] * L2E;

  const floatx4 zero4 = {0.f, 0.f, 0.f, 0.f};
  bf16x8 ones;
  { uint4 t4; t4.x = t4.y = t4.z = t4.w = 0x3F803F80u; ones = __builtin_bit_cast(bf16x8, t4); }

  // Q fragment: load raw fp32 (B,L,H,E), RoPE, convert to bf16 B-frag
  bf16x8 qf[2];
  {
    const float* qrow = Q + (((size_t)(b * L_ + row0 + l16)) * H_ + h) * E_;
#pragma unroll
    for (int hf = 0; hf < 2; ++hf) {
      const float* p = qrow + hf * 32 + quad * 8;
      float4 A = *(const float4*)p, Bv = *(const float4*)(p + 4);
      float x[8] = {A.x, A.y, A.z, A.w, Bv.x, Bv.y, Bv.z, Bv.w};
      if (hf == 0) rope_pairs(x, (float)(row0 + l16), quad * 4);
      uint4 o;
      o.x = pk2bf(x[0], x[1]); o.y = pk2bf(x[2], x[3]);
      o.z = pk2bf(x[4], x[5]); o.w = pk2bf(x[6], x[7]);
      qf[hf] = __builtin_bit_cast(bf16x8, o);
    }
  }

  floatx4 oacc[4];
  floatx4 lacc = zero4;
#pragma unroll
  for (int c4 = 0; c4 < 4; ++c4) oacc[c4] = zero4;

  u32* const prow = &pabuf[wid][l16 * 20];

  bf16x8 ka[2][2], va[4], kb2[2][2], vb2[4];

  auto loadKV = [&](int ti, bf16x8(&kf)[2][2], bf16x8(&vf)[4]) {
    const int k0 = ti << shift;
#pragma unroll
    for (int ch = 0; ch < 2; ++ch)
#pragma unroll
      for (int hf = 0; hf < 2; ++hf)
        kf[ch][hf] = *(const bf16x8*)(Kb + (((size_t)(k0 + ch * 16 + l16)) << 6) + hf * 32 + quad * 8);
#pragma unroll
    for (int c4 = 0; c4 < 4; ++c4)
      vf[c4] = *(const bf16x8*)(Vb + (((size_t)(c4 * 16 + l16)) << 11) + k0 + quad * 8);
  };

  auto step = [&](int t, bf16x8(&kc)[2][2], bf16x8(&vc)[4],
                  bf16x8(&kn)[2][2], bf16x8(&vn)[4]) {
    const int k0 = t << shift;
    const int v = k0 >> 6;
    // S^T tiles: 2x (16 s x 16 q)
    floatx4 a0 = __builtin_amdgcn_mfma_f32_16x16x32_bf16(kc[0][0], qf[0], zero4, 0, 0, 0);
    floatx4 ss0 = __builtin_amdgcn_mfma_f32_16x16x32_bf16(kc[0][1], qf[1], a0, 0, 0, 0);
    floatx4 a1 = __builtin_amdgcn_mfma_f32_16x16x32_bf16(kc[1][0], qf[0], zero4, 0, 0, 0);
    floatx4 ss1 = __builtin_amdgcn_mfma_f32_16x16x32_bf16(kc[1][1], qf[1], a1, 0, 0, 0);
    // prefetch next step's K,V while the exp/LDS phase runs
    int tn = t + 1;
    if (tn >= T) tn = 0;  // wrap: harmless extra load, keeps code uniform
    loadKV(tn, kn, vn);
    // P = exp2(scale*l2e*S + bias*l2e), causal-within-64 mask, pack to A-layout LDS
    const float bl2 = (v == var_l) ? bls : bld;
    const bool domask = ((k0 & 63) + 31) > t0;
    const int tsb = (k0 & 63) + quad * 4 - t0 - l16;  // masked iff tsb+ch*16+r > 0
#pragma unroll
    for (int ch = 0; ch < 2; ++ch) {
      const floatx4 ssv = ch ? ss1 : ss0;
      float pv[4];
#pragma unroll
      for (int r = 0; r < 4; ++r) {
        float p = exp2f(ssv[r] * SCL2 + bl2);
        if (domask && (tsb + ch * 16 + r > 0)) p = 0.0f;
        pv[r] = p;
      }
      *(uint2*)(prow + ch * 8 + quad * 2) =
          make_uint2(pk2bf(pv[0], pv[1]), pk2bf(pv[2], pv[3]));
    }
    __asm__ volatile("s_waitcnt lgkmcnt(0)" ::: "memory");
    bf16x8 pa = *(const bf16x8*)(prow + quad * 4);
    lacc = __builtin_amdgcn_mfma_f32_16x16x32_bf16(pa, ones, lacc, 0, 0, 0);
#pragma unroll
    for (int c4 = 0; c4 < 4; ++c4)
      oacc[c4] = __builtin_amdgcn_mfma_f32_16x16x32_bf16(pa, vc[c4], oacc[c4], 0, 0, 0);
  };

  loadKV(0, ka, va);
  for (int t = 0; t < T; t += 2) {
    step(t, ka, va, kb2, vb2);
    step(t + 1, kb2, vb2, ka, va);
  }

  // epilogue: O rows = quad*4+reg (aligned with lacc rows), cols = c4*16+l16
  floatx4 rv;
#pragma unroll
  for (int r = 0; r < 4; ++r) rv[r] = 1.0f / lacc[r];
#pragma unroll
  for (int r = 0; r < 4; ++r) {
    const int row = row0 + quad * 4 + r;
    float* dst = out + (((size_t)(b * L_ + row)) * H_ + h) * E_ + l16;
#pragma unroll
    for (int c4 = 0; c4 < 4; ++c4) dst[c4 * 16] = oacc[c4][r] * rv[r];
  }
}

extern "C" void kernel_launch(void* const* d_in, const int* in_sizes, int n_in,
                              void* d_out, int out_size, void* d_ws, size_t ws_size,
                              hipStream_t stream) {
  (void)in_sizes; (void)n_in; (void)out_size; (void)ws_size;
  const float* q = (const float*)d_in[0];
  const float* k = (const float*)d_in[1];
  const float* v = (const float*)d_in[2];
  const float* bwp = (const float*)d_in[3];
  // d_in[4]=n_vars(=32), d_in[5]=n_tokens(=64): fixed by setup, hardcoded.
  float* out = (float*)d_out;
  u16* Kr = (u16*)d_ws;            // 8 MB
  u16* VT = Kr + QK_ELEMS;         // 8 MB (ws >= 24 MB confirmed in R3: path A ran)
  rope_k<<<(B_ * L_ * H_) / 32, 256, 0, stream>>>(k, Kr);
  transpose_v<<<B_ * H_ * (L_ / 64), 256, 0, stream>>>(v, VT);
  flash<<<1024, 256, 0, stream>>>(q, Kr, VT, bwp, out);
}

// Round 5
// 217.634 us; speedup vs baseline: 1.5040x; 1.5040x over previous
//
#include <hip/hip_runtime.h>

typedef unsigned short u16;
typedef unsigned int u32;

typedef __attribute__((ext_vector_type(8))) __bf16 bf16x8;
typedef __attribute__((ext_vector_type(4))) float floatx4;

#define B_ 2
#define L_ 2048
#define H_ 16
#define E_ 64
#define QK_ELEMS (B_ * L_ * H_ * E_) /* 4194304 elems; bf16 = 8 MB */

static __device__ __forceinline__ u32 pk2bf(float a, float b) {
  u32 ua = __builtin_bit_cast(u32, a), ub = __builtin_bit_cast(u32, b);
  return ((ua + 0x8000u) >> 16) | (((ub + 0x8000u) >> 16) << 16);
}
static __device__ __forceinline__ u16 f2bf1(float a) {
  return (u16)((__builtin_bit_cast(u32, a) + 0x8000u) >> 16);
}

// RoPE 4 pairs in fp32: pair m uses freq idx pbase+m, theta=10000^(-j/16).
// v_sin/v_cos take revolutions; fract keeps arg in range (err ~2e-4 rad @ l=2047).
static __device__ __forceinline__ void rope_pairs(float* x, float pos, int pbase) {
  const float LB = 0.83048202372184058696f;   // log2(10000)/16
  const float I2P = 0.15915494309189533577f;  // 1/(2*pi)
#pragma unroll
  for (int m = 0; m < 4; ++m) {
    float fr = exp2f(-(float)(pbase + m) * LB) * I2P;
    float a = pos * fr;
    a -= floorf(a);
    float s = __builtin_amdgcn_sinf(a);
    float c = __builtin_amdgcn_cosf(a);
    float e0 = x[2 * m], e1 = x[2 * m + 1];
    x[2 * m] = c * e0 - s * e1;
    x[2 * m + 1] = c * e1 + s * e0;
  }
}

// ---------- fused prepass: [0,2048) RoPE K -> bf16 (B,H,L,E); [2048,3072) V -> VT bf16 (B,H,E,L)
__global__ __launch_bounds__(256) void prep(const float* __restrict__ K,
                                            const float* __restrict__ V,
                                            u16* __restrict__ Kr,
                                            u16* __restrict__ VT) {
  __shared__ u16 tile[64][65];
  int t = threadIdx.x;
  if (blockIdx.x < 2048) {
    int R = blockIdx.x * 32 + (t >> 3);     // row id in (b,l,h) order
    int chunk = t & 7, e0 = chunk << 3;
    int b = R >> 15, l = (R >> 4) & (L_ - 1), h = R & 15;
    const float* src = K + ((size_t)R << 6) + e0;
    float4 A = *(const float4*)src, Bv = *(const float4*)(src + 4);
    float x[8] = {A.x, A.y, A.z, A.w, Bv.x, Bv.y, Bv.z, Bv.w};
    if (chunk < 4) rope_pairs(x, (float)l, chunk * 4);  // dims < 32 rotate
    uint4 o;
    o.x = pk2bf(x[0], x[1]); o.y = pk2bf(x[2], x[3]);
    o.z = pk2bf(x[4], x[5]); o.w = pk2bf(x[6], x[7]);
    *(uint4*)(Kr + (((size_t)(b * H_ + h) * L_ + l) << 6) + e0) = o;
  } else {
    int blk = blockIdx.x - 2048;      // 32 bh * 32 ltiles
    int bh = blk & 31, lt = blk >> 5;
    int b = bh >> 4, h = bh & 15;
    int l0 = lt << 6;
#pragma unroll
    for (int it = 0; it < 2; ++it) {
      int ll = (t >> 3) + (it << 5);
      int dc = (t & 7) << 3;
      const float* src = V + (((size_t)(b * L_ + l0 + ll) * H_ + h) << 6) + dc;
      float4 A = *(const float4*)src, Bv = *(const float4*)(src + 4);
      tile[ll][dc + 0] = f2bf1(A.x); tile[ll][dc + 1] = f2bf1(A.y);
      tile[ll][dc + 2] = f2bf1(A.z); tile[ll][dc + 3] = f2bf1(A.w);
      tile[ll][dc + 4] = f2bf1(Bv.x); tile[ll][dc + 5] = f2bf1(Bv.y);
      tile[ll][dc + 6] = f2bf1(Bv.z); tile[ll][dc + 7] = f2bf1(Bv.w);
    }
    __syncthreads();
    int e = t >> 2, lg = (t & 3) << 4;
    u32 pk[8];
#pragma unroll
    for (int i = 0; i < 8; ++i)
      pk[i] = (u32)tile[lg + 2 * i][e] | ((u32)tile[lg + 2 * i + 1][e] << 16);
    u16* dst = VT + (((size_t)bh * E_ + e) * L_) + l0 + lg;
    uint4 o0; o0.x = pk[0]; o0.y = pk[1]; o0.z = pk[2]; o0.w = pk[3];
    uint4 o1; o1.x = pk[4]; o1.y = pk[5]; o1.z = pk[6]; o1.w = pk[7];
    *(uint4*)dst = o0;
    *(uint4*)(dst + 8) = o1;
  }
}

// ---------- main flash kernel ----------
// 32 q-rows/wave (2 rh), 32-key steps, keys split 4-way across waves (static-max
// softmax => O/l partials are pure sums; combined via device-scope f32 atomics).
// mfma_f32_16x16x32_bf16 lane maps (m89/m120-verified):
//   A[m=lane&15][k=quad*8+j]  B[k=quad*8+j][n=lane&15]  C/D: col=lane&15, row=quad*4+reg
// S^T = MFMA(A=K, B=Q): lane holds S[s=quad*4+reg][q=l16] -> consecutive s in regs
// -> pack pairs in-register -> 4x ds_write_b64 -> 2x ds_read_b128 in A-layout.
// Mask threshold is step-invariant (t0 cancels): masked iff reg > mth[ch][rh] on last kt.
__global__ __launch_bounds__(256, 4) void flash(
    const float* __restrict__ Q, const u16* __restrict__ Kr,
    const u16* __restrict__ VT, const float* __restrict__ bw,
    float* __restrict__ lbuf, float* __restrict__ out) {
  __shared__ __align__(16) u32 pabuf[4 * 2 * 640];  // wave x pingpong x (2rh*16*20)
  const int tid = threadIdx.x;
  const int wid = tid >> 6, lane = tid & 63;
  const int quad = lane >> 4, l16 = lane & 15;
  const int bh = blockIdx.x & 31;       // low bits -> XCD round-robin L2 locality
  const int r5 = blockIdx.x >> 5;       // 0..63
  const int rbpair = r5 & 31, cpair = r5 >> 5;
  const int rowblk = rbpair * 2 + (wid & 1);   // 0..63
  const int chunk = cpair * 2 + (wid >> 1);    // 0..3: vars 8c..8c+7
  const int row0 = rowblk << 5;
  const int nst = 1 + (wid & 1);        // t0=0 -> 1 step/var, t0=32 -> 2 (block total 48: balanced)
  const int b = bh >> 4, h = bh & 15;

  const u16* Kb = Kr + ((size_t)bh << 17);
  const u16* Vb = VT + ((size_t)bh << 17);

  const float bd = bw[h], bs = bw[H_ + h];

  const floatx4 zero4 = {0.f, 0.f, 0.f, 0.f};
  bf16x8 ones;
  { uint4 t4; t4.x = t4.y = t4.z = t4.w = 0x3F803F80u; ones = __builtin_bit_cast(bf16x8, t4); }

  // Q B-frags (n=l16 = q), RoPE fused once
  bf16x8 qf[2][2];
#pragma unroll
  for (int rh = 0; rh < 2; ++rh) {
    const int row = row0 + rh * 16 + l16;
    const float* qrow = Q + (((size_t)(b * L_ + row)) * H_ + h) * E_;
#pragma unroll
    for (int hf = 0; hf < 2; ++hf) {
      const float* p = qrow + hf * 32 + quad * 8;
      float4 A = *(const float4*)p, Bv = *(const float4*)(p + 4);
      float x[8] = {A.x, A.y, A.z, A.w, Bv.x, Bv.y, Bv.z, Bv.w};
      if (hf == 0) rope_pairs(x, (float)row, quad * 4);
      uint4 o;
      o.x = pk2bf(x[0], x[1]); o.y = pk2bf(x[2], x[3]);
      o.z = pk2bf(x[4], x[5]); o.w = pk2bf(x[6], x[7]);
      qf[rh][hf] = __builtin_bit_cast(bf16x8, o);
    }
  }

  int mth[2][2];
#pragma unroll
  for (int ch = 0; ch < 2; ++ch)
#pragma unroll
    for (int rh = 0; rh < 2; ++rh)
      mth[ch][rh] = rh * 16 + l16 - ch * 16 - quad * 4;

  floatx4 oacc[2][4], lacc[2];
#pragma unroll
  for (int rh = 0; rh < 2; ++rh) {
    lacc[rh] = zero4;
#pragma unroll
    for (int c4 = 0; c4 < 4; ++c4) oacc[rh][c4] = zero4;
  }

  u32* const pw0 = pabuf + wid * 1280;
  int pp = 0;

  for (int i = 0; i < 8; ++i) {
    const int v = chunk * 8 + i;
    const float bias = (v == rbpair) ? bs : bd;
    for (int kt = 0; kt < nst; ++kt) {
      const int k0 = (v << 6) + (kt << 5);

      bf16x8 kf[2][2], vf[4];
#pragma unroll
      for (int ch = 0; ch < 2; ++ch)
#pragma unroll
        for (int hf = 0; hf < 2; ++hf)
          kf[ch][hf] = *(const bf16x8*)(Kb + ((k0 + ch * 16 + l16) << 6) + hf * 32 + quad * 8);
#pragma unroll
      for (int c4 = 0; c4 < 4; ++c4)
        vf[c4] = *(const bf16x8*)(Vb + ((c4 * 16 + l16) << 11) + k0 + quad * 8);

      floatx4 cc[2][2];
#pragma unroll
      for (int ch = 0; ch < 2; ++ch)
#pragma unroll
        for (int rh = 0; rh < 2; ++rh) {
          floatx4 acc = __builtin_amdgcn_mfma_f32_16x16x32_bf16(kf[ch][0], qf[rh][0], zero4, 0, 0, 0);
          cc[ch][rh] = __builtin_amdgcn_mfma_f32_16x16x32_bf16(kf[ch][1], qf[rh][1], acc, 0, 0, 0);
        }

      u32* const pw = pw0 + pp * 640;
      const bool dm = (kt == nst - 1);
#pragma unroll
      for (int ch = 0; ch < 2; ++ch)
#pragma unroll
        for (int rh = 0; rh < 2; ++rh) {
          const floatx4 c = cc[ch][rh];
          float pv[4];
#pragma unroll
          for (int r = 0; r < 4; ++r) {
            float p = __expf(c[r] * 0.125f + bias);
            if (dm && (r > mth[ch][rh])) p = 0.0f;
            pv[r] = p;
          }
          *(uint2*)(pw + rh * 320 + l16 * 20 + ch * 8 + quad * 2) =
              make_uint2(pk2bf(pv[0], pv[1]), pk2bf(pv[2], pv[3]));
        }

      __asm__ volatile("s_waitcnt lgkmcnt(0)" ::: "memory");

      bf16x8 pa[2];
#pragma unroll
      for (int rh = 0; rh < 2; ++rh)
        pa[rh] = *(const bf16x8*)(pw + rh * 320 + l16 * 20 + quad * 4);

#pragma unroll
      for (int rh = 0; rh < 2; ++rh)
        lacc[rh] = __builtin_amdgcn_mfma_f32_16x16x32_bf16(pa[rh], ones, lacc[rh], 0, 0, 0);
#pragma unroll
      for (int c4 = 0; c4 < 4; ++c4)
#pragma unroll
        for (int rh = 0; rh < 2; ++rh)
          oacc[rh][c4] = __builtin_amdgcn_mfma_f32_16x16x32_bf16(pa[rh], vf[c4], oacc[rh][c4], 0, 0, 0);
      pp ^= 1;
    }
  }

  // epilogue: O C-layout rows q = quad*4+reg (lacc rows align). Accumulate partials.
  if (l16 == 0) {
#pragma unroll
    for (int rh = 0; rh < 2; ++rh)
#pragma unroll
      for (int r = 0; r < 4; ++r) {
        int q = row0 + rh * 16 + quad * 4 + r;
        __hip_atomic_fetch_add(&lbuf[(b * H_ + h) * L_ + q], lacc[rh][r],
                               __ATOMIC_RELAXED, __HIP_MEMORY_SCOPE_AGENT);
      }
  }
#pragma unroll
  for (int rh = 0; rh < 2; ++rh)
#pragma unroll
    for (int r = 0; r < 4; ++r) {
      const int row = row0 + rh * 16 + quad * 4 + r;
      float* dst = out + (((size_t)(b * L_ + row)) * H_ + h) * E_ + l16;
#pragma unroll
      for (int c4 = 0; c4 < 4; ++c4)
        __hip_atomic_fetch_add(dst + c4 * 16, oacc[rh][c4][r],
                               __ATOMIC_RELAXED, __HIP_MEMORY_SCOPE_AGENT);
    }
}

// ---------- normalize: out /= l ----------
__global__ __launch_bounds__(256) void normalize(const float* __restrict__ lbuf,
                                                 float* __restrict__ out) {
  int i = blockIdx.x * 256 + threadIdx.x;   // float4 index
  int f = i << 2;
  int h = (f >> 6) & 15, row = (f >> 10) & (L_ - 1), b = f >> 21;
  float rv = 1.0f / lbuf[(b * H_ + h) * L_ + row];
  float4* p = (float4*)out + i;
  float4 x = *p;
  x.x *= rv; x.y *= rv; x.z *= rv; x.w *= rv;
  *p = x;
}

extern "C" void kernel_launch(void* const* d_in, const int* in_sizes, int n_in,
                              void* d_out, int out_size, void* d_ws, size_t ws_size,
                              hipStream_t stream) {
  (void)in_sizes; (void)n_in; (void)ws_size;
  const float* q = (const float*)d_in[0];
  const float* k = (const float*)d_in[1];
  const float* v = (const float*)d_in[2];
  const float* bwp = (const float*)d_in[3];
  // d_in[4]=n_vars(=32), d_in[5]=n_tokens(=64): fixed by setup, hardcoded.
  float* out = (float*)d_out;
  u16* Kr = (u16*)d_ws;                                  // 8 MB
  u16* VT = Kr + QK_ELEMS;                               // 8 MB
  float* lbuf = (float*)((char*)d_ws + 2 * (size_t)QK_ELEMS * sizeof(u16));  // 256 KB
  hipMemsetAsync(d_out, 0, (size_t)out_size * sizeof(float), stream);
  hipMemsetAsync(lbuf, 0, (size_t)(B_ * H_ * L_) * sizeof(float), stream);
  prep<<<3072, 256, 0, stream>>>(k, v, Kr, VT);
  flash<<<2048, 256, 0, stream>>>(q, Kr, VT, bwp, lbuf, out);
  normalize<<<4096, 256, 0, stream>>>(lbuf, out);
}